// Round 7
// baseline (774.970 us; speedup 1.0000x reference)
//
#include <hip/hip_runtime.h>
#include <hip/hip_bf16.h>
#include <math.h>

#define Bc 8
#define Sc 4
#define Nc 64
#define AF 133
#define BFD 147
#define Hc 300
#define BS (Bc*Sc)                  // 32
#define ROWS (BS*Nc)                // 2048 atom rows
#define EDGES (BS*Nc*Nc)            // 131072 edges
#define BSLICE 19456                // shorts per kt-slice of WP: 2*19*64*8
#define BHALF  9728                 // 19*64*8

typedef float f32x4 __attribute__((ext_vector_type(4)));
typedef short bf16x8 __attribute__((ext_vector_type(8)));
typedef float f32x4v __attribute__((ext_vector_type(4)));
typedef f32x4v f32x4u __attribute__((aligned(4)));   // 4B-aligned float4 (f_bonds rows are 588B)
union U4 { uint4 u; bf16x8 v; };

__device__ __forceinline__ float reluf(float x){ return fmaxf(x, 0.f); }
__device__ __forceinline__ float b2f(unsigned short u){ union{unsigned int i;float f;}v; v.i = ((unsigned int)u)<<16; return v.f; }
__device__ __forceinline__ unsigned short f2b(float f){ __hip_bfloat16 h = __float2bfloat16(f); return *reinterpret_cast<unsigned short*>(&h); }
__device__ __forceinline__ void split2(float x, unsigned short &hi, unsigned short &lo){
    unsigned short h = f2b(x);
    float r = x - b2f(h);
    hi = h; lo = f2b(r);
}

typedef __attribute__((address_space(1))) const unsigned int* gas1_t;
typedef __attribute__((address_space(3))) unsigned int* las3_t;
__device__ __forceinline__ void gload_lds16(const void* g, void* l){
    __builtin_amdgcn_global_load_lds((gas1_t)g, (las3_t)l, 16, 0, 0);
}

// raw barrier, no counter drain (A-prefetch stays in flight across it)
__device__ __forceinline__ void bar_only(){
    __builtin_amdgcn_sched_barrier(0);
    asm volatile("" ::: "memory");
    __builtin_amdgcn_s_barrier();
    asm volatile("" ::: "memory");
    __builtin_amdgcn_sched_barrier(0);
}
// barrier draining vm (copyB gload_lds) + lgkm (buildA ds_writes) only
__device__ __forceinline__ void bar_drain(){
    __builtin_amdgcn_sched_barrier(0);
    asm volatile("s_waitcnt vmcnt(0) lgkmcnt(0)" ::: "memory");
    __builtin_amdgcn_s_barrier();
    asm volatile("" ::: "memory");
    __builtin_amdgcn_sched_barrier(0);
}

// ---------------- K1: input_atom = relu(f_atoms @ W_i_atom); message_atom = copy (4 rows/block)
#define RA 4
__global__ __launch_bounds__(320) void k_atom_embed(const float* __restrict__ f_atoms,
        const float* __restrict__ W, float* __restrict__ input_atom, float* __restrict__ message_atom){
    __shared__ float x[RA][AF];
    int r0 = blockIdx.x * RA;
    for (int idx = threadIdx.x; idx < RA*AF; idx += blockDim.x){
        int r = idx / AF, d = idx - r*AF;
        x[r][d] = f_atoms[(size_t)(r0+r)*AF + d];
    }
    __syncthreads();
    int h = threadIdx.x;
    if (h < Hc){
        float acc[RA];
        #pragma unroll
        for (int r = 0; r < RA; ++r) acc[r] = 0.f;
        for (int d = 0; d < AF; ++d){
            float w = W[d*Hc + h];
            #pragma unroll
            for (int r = 0; r < RA; ++r) acc[r] = fmaf(x[r][d], w, acc[r]);
        }
        #pragma unroll
        for (int r = 0; r < RA; ++r){
            float v = reluf(acc[r]);
            input_atom[(size_t)(r0+r)*Hc + h] = v;
            message_atom[(size_t)(r0+r)*Hc + h] = v;
        }
    }
}

// ---------------- merged prep: {W_h0, W_h1, W_i_bond} -> split bf16 WP0|WP1|WPb (contiguous)
__global__ __launch_bounds__(256) void k_prep_all(const float* __restrict__ W_h0,
        const float* __restrict__ W_h1, const float* __restrict__ W_ib,
        unsigned short* __restrict__ WP){
    int idx = blockIdx.x*256 + threadIdx.x;
    if (idx >= 25*BSLICE) return;
    const float* W; int K; int lidx;
    if (idx < 10*BSLICE){ W = W_h0; K = Hc; lidx = idx; }
    else if (idx < 20*BSLICE){ W = W_h1; K = Hc; lidx = idx - 10*BSLICE; }
    else { W = W_ib; K = BFD; lidx = idx - 20*BSLICE; }
    int j  = lidx & 7;
    int l  = (lidx >> 3) & 63;
    int ct = (lidx >> 9) % 19;
    int rem = lidx / BHALF;
    int hl = rem & 1;
    int kt = rem >> 1;
    int col = ct*16 + (l & 15);
    int k   = kt*32 + (l >> 4)*8 + j;
    float v = (col < Hc && k < K) ? W[k*Hc + col] : 0.f;
    unsigned short hi, lo; split2(v, hi, lo);
    WP[idx] = hl ? lo : hi;
}

// ---------------- tiled split-bf16 MFMA edge GEMM (128 rows x 304 cols per block) — R3-exact
// MODE 0: column-pair blocks (b,s fixed; cols m0=2*mp, m1): ib = relu((adj*f_bonds)@W_i_bond)
//         + FUSED agg: message_atom[m] += (sum_n v)*sigmoid(max_n v)   (block owns cols)
// MODE 2: column-pair blocks, out-of-place: dst = relu(ib + A@W_h)*sm
//         A-row for output (n,m): adj[(m,n)]*ma[n] - mb_old[(m,n)]  (contiguous row reads)
//         + FUSED agg -> aggb (=)
// MODE 1: closed-pair blocks, in-place (fallback), no agg fusion
template<int MODE>
__global__ __launch_bounds__(1024) void k_gemm_t(
        const float* __restrict__ Asrc,          // M0: f_bonds [E][147]; M1/M2: mb_old [E][300]
        const unsigned short* __restrict__ WP,   // [NKT][2][19][64][8]
        const float* __restrict__ ma,
        const float* __restrict__ adj,
        const float* __restrict__ sm,
        const float* __restrict__ ib,
        float* __restrict__ dst,
        float* __restrict__ aggb)                // M0: message_atom (+=); M2: agg buffer (=)
{
    constexpr int NKT  = (MODE != 0) ? 10 : 5;
    constexpr int ASTR = (MODE != 0) ? 300 : BFD;

    __shared__ unsigned short sAhi[4096];        // 128 rows x 32 k (chunked)
    __shared__ unsigned short sAlo[4096];
    __shared__ unsigned short sB[BSLICE];        // hi block then lo block
    __shared__ int s_eOut[128];
    __shared__ int s_eRev[128];
    __shared__ float s_adjRev[128];
    __shared__ int s_aAtom[128];

    const int t = threadIdx.x;
    const int bs0 = blockIdx.x >> 5;             // MODE0/2: (b,s) slab
    const int mp0 = blockIdx.x & 31;             // MODE0/2: column pair (m0=2*mp0, m1=m0+1)

    if constexpr (MODE == 1){
        if (t < 128){
            int r = t;
            int bs = bs0, kk = mp0;
            int s1 = 64-kk, s2 = 127-2*kk, s3 = 128-kk;
            int a, b;
            if (r < s1){ a = kk; b = kk + r; }
            else if (r < s2){ a = kk+1 + (r - s1); b = kk; }
            else if (r < s3){ a = 63-kk; b = 63-kk + (r - s2); }
            else { a = 64-kk + (r - s3); b = 63-kk; }
            int eo = (bs*64 + a)*64 + b;
            int er = (bs*64 + b)*64 + a;
            s_eOut[r] = eo; s_eRev[r] = er; s_aAtom[r] = bs*64 + a;
            s_adjRev[r] = adj[er];
        }
        __syncthreads();
    }

    // ---- A-build role: thread t -> row brow, k-offset koff (4 floats), LDS shorts [4t..4t+3]
    const int rt_b = t >> 7;
    const int q_b  = (t >> 5) & 3;
    const int li_b = (t >> 1) & 15;
    const int half = t & 1;
    const int brow = rt_b*16 + li_b;
    const int koff = q_b*8 + 4*half;
    const float* aRow;
    const float* mRow = nullptr;
    float adjR = 0.f;
    if constexpr (MODE == 1){
        aRow = Asrc + (size_t)s_eRev[brow]*ASTR;
        mRow = ma + (size_t)s_aAtom[brow]*Hc;
        adjR = s_adjRev[brow];
    } else if constexpr (MODE == 2){
        int n = brow & 63, cc = brow >> 6;
        int eR = (bs0*64 + (2*mp0 + cc))*64 + n;       // row (m,n): contiguous per cc
        aRow = Asrc + (size_t)eR*ASTR;
        mRow = ma + (size_t)(bs0*64 + n)*Hc;
        adjR = adj[eR];
    } else {
        int n = brow & 63, cc = brow >> 6;
        int e = (bs0*64 + n)*64 + (2*mp0 + cc);        // output edge itself
        aRow = Asrc + (size_t)e*ASTR;
        adjR = adj[e];
    }

    float pm[4], pa[4];
    auto prefetchA = [&](int kt){
        int k0 = kt*32 + koff;
        if constexpr (MODE != 0){
            if (k0 <= 296){
                float4 v = *(const float4*)(aRow + k0);   // rows 1200B -> 16B aligned
                float4 w = *(const float4*)(mRow + k0);
                pm[0]=v.x; pm[1]=v.y; pm[2]=v.z; pm[3]=v.w;
                pa[0]=w.x; pa[1]=w.y; pa[2]=w.z; pa[3]=w.w;
            }
        } else {
            if (k0 + 3 < BFD){
                f32x4u v = *(const f32x4u*)(aRow + k0);   // 4B-aligned dwordx4
                pm[0]=v.x; pm[1]=v.y; pm[2]=v.z; pm[3]=v.w;
            } else {
                #pragma unroll
                for (int j = 0; j < 4; ++j){
                    int k = k0 + j;
                    pm[j] = (k < BFD) ? aRow[k] : 0.f;
                }
            }
        }
    };
    auto buildA = [&](int kt){
        int k0 = kt*32 + koff;
        float xv[4];
        if constexpr (MODE != 0){
            if (k0 <= 296){
                #pragma unroll
                for (int j = 0; j < 4; ++j) xv[j] = fmaf(adjR, pa[j], -pm[j]);
            } else { xv[0]=xv[1]=xv[2]=xv[3]=0.f; }
        } else {
            #pragma unroll
            for (int j = 0; j < 4; ++j) xv[j] = adjR * pm[j];
        }
        unsigned short h0,l0,h1,l1,h2,l2,h3,l3;
        split2(xv[0],h0,l0); split2(xv[1],h1,l1);
        split2(xv[2],h2,l2); split2(xv[3],h3,l3);
        uint2 hw, lw;
        hw.x = (unsigned int)h0 | ((unsigned int)h1<<16);
        hw.y = (unsigned int)h2 | ((unsigned int)h3<<16);
        lw.x = (unsigned int)l0 | ((unsigned int)l1<<16);
        lw.y = (unsigned int)l2 | ((unsigned int)l3<<16);
        *(uint2*)&sAhi[4*t] = hw;        // byte 8t: bank-linear, conflict-free
        *(uint2*)&sAlo[4*t] = lw;
    };
    auto copyB = [&](int kt){
        const unsigned short* src = WP + (size_t)kt*BSLICE;
        #pragma unroll
        for (int rep = 0; rep < 3; ++rep){
            int i = t + rep*1024;
            if (i < BSLICE/8)
                gload_lds16(src + (size_t)i*8, &sB[i*8]);
        }
    };

    // ---- compute role
    const int wv = t >> 6, lane = t & 63;
    const int li = lane & 15, quad = lane >> 4;
    const int rg = wv & 3;                       // row-tiles 2rg, 2rg+1
    const int cg = wv >> 2;
    const int c0 = cg*5;
    const int myC = (cg < 3) ? 5 : 4;

    f32x4 acc[5][2];
    #pragma unroll
    for (int c = 0; c < 5; ++c){ acc[c][0] = (f32x4){0,0,0,0}; acc[c][1] = (f32x4){0,0,0,0}; }

    prefetchA(0);

    // MODE1/2: preload ib into acc (epilogue loads vanish; overlaps kt0 staging)
    if constexpr (MODE != 0){
        #pragma unroll
        for (int c = 0; c < 5; ++c){
            if (c < myC){
                int h = (c0 + c)*16 + li;
                if (h < Hc){
                    #pragma unroll
                    for (int r2 = 0; r2 < 2; ++r2)
                        #pragma unroll
                        for (int i = 0; i < 4; ++i){
                            int row = (2*rg + r2)*16 + quad*4 + i;
                            int e;
                            if constexpr (MODE == 1) e = s_eOut[row];
                            else e = (bs0*64 + (row & 63))*64 + (2*mp0 + (row >> 6));
                            acc[c][r2][i] = ib[(size_t)e*Hc + h];
                        }
                }
            }
        }
    }

    for (int kt = 0; kt < NKT; ++kt){
        if (kt) bar_only();                      // B1: pure barrier (prefetchA stays in flight)
        copyB(kt);                               // 3 async gload_lds (L2-hot)
        buildA(kt);                              // consumes pm/pa (compiler-counted vmcnt)
        bar_drain();                             // vmcnt(0)+lgkm(0): copyB + sA writes visible
        if (kt+1 < NKT) prefetchA(kt+1);         // HBM latency spans full compute(kt) + B1
        __builtin_amdgcn_s_setprio(1);
        U4 a0h, a0l, a1h, a1l;
        a0h.u = *(const uint4*)&sAhi[((2*rg  )*64 + lane)*8];
        a0l.u = *(const uint4*)&sAlo[((2*rg  )*64 + lane)*8];
        a1h.u = *(const uint4*)&sAhi[((2*rg+1)*64 + lane)*8];
        a1l.u = *(const uint4*)&sAlo[((2*rg+1)*64 + lane)*8];
        #pragma unroll
        for (int c = 0; c < 5; ++c){
            if (c < myC){
                U4 bh, bl;
                bh.u = *(const uint4*)&sB[        (c0+c)*512 + lane*8];
                bl.u = *(const uint4*)&sB[BHALF + (c0+c)*512 + lane*8];
                acc[c][0] = __builtin_amdgcn_mfma_f32_16x16x32_bf16(a0h.v, bl.v, acc[c][0], 0,0,0);
                acc[c][0] = __builtin_amdgcn_mfma_f32_16x16x32_bf16(a0l.v, bh.v, acc[c][0], 0,0,0);
                acc[c][0] = __builtin_amdgcn_mfma_f32_16x16x32_bf16(a0h.v, bh.v, acc[c][0], 0,0,0);
                acc[c][1] = __builtin_amdgcn_mfma_f32_16x16x32_bf16(a1h.v, bl.v, acc[c][1], 0,0,0);
                acc[c][1] = __builtin_amdgcn_mfma_f32_16x16x32_bf16(a1l.v, bh.v, acc[c][1], 0,0,0);
                acc[c][1] = __builtin_amdgcn_mfma_f32_16x16x32_bf16(a1h.v, bh.v, acc[c][1], 0,0,0);
            }
        }
        __builtin_amdgcn_s_setprio(0);
    }

    if constexpr (MODE == 1){
        // ---- closed-pair epilogue: stores only
        int eO[2][4]; float smv[2][4];
        #pragma unroll
        for (int r2 = 0; r2 < 2; ++r2)
            #pragma unroll
            for (int i = 0; i < 4; ++i){
                int row = (2*rg + r2)*16 + quad*4 + i;
                int e = s_eOut[row];
                eO[r2][i] = e;
                smv[r2][i] = sm[e];
            }
        #pragma unroll
        for (int c = 0; c < 5; ++c){
            if (c >= myC) continue;
            int h = (c0 + c)*16 + li;
            if (h >= Hc) continue;
            #pragma unroll
            for (int r2 = 0; r2 < 2; ++r2)
                #pragma unroll
                for (int i = 0; i < 4; ++i){
                    size_t off = (size_t)eO[r2][i]*Hc + h;
                    dst[off] = reluf(acc[c][r2][i]) * smv[r2][i];
                }
        }
    } else {
        // ---- column-pair epilogue: store + fused column reduction (agg)
        __syncthreads();                          // all sB reads done -> reuse sB as sRed
        float* sRedS = (float*)sB;                // [16 waves][304]
        float* sRedM = sRedS + 16*304;
        int eO[2][4]; float smv[2][4];
        #pragma unroll
        for (int r2 = 0; r2 < 2; ++r2)
            #pragma unroll
            for (int i = 0; i < 4; ++i){
                int row = (2*rg + r2)*16 + quad*4 + i;
                int e = (bs0*64 + (row & 63))*64 + (2*mp0 + (row >> 6));
                eO[r2][i] = e;
                if constexpr (MODE == 2) smv[r2][i] = sm[e];
            }
        #pragma unroll
        for (int c = 0; c < 5; ++c){
            float s8 = 0.f, m8 = -INFINITY;
            int h = (c0 + c)*16 + li;
            if (c < myC && h < Hc){
                #pragma unroll
                for (int r2 = 0; r2 < 2; ++r2)
                    #pragma unroll
                    for (int i = 0; i < 4; ++i){
                        float v = reluf(acc[c][r2][i]);
                        if constexpr (MODE == 2) v *= smv[r2][i];
                        dst[(size_t)eO[r2][i]*Hc + h] = v;
                        s8 += v; m8 = fmaxf(m8, v);
                    }
            }
            // butterfly across quads (lane bits 4,5): 32-row partial per (wave, h)
            s8 += __shfl_xor(s8, 16, 64); s8 += __shfl_xor(s8, 32, 64);
            m8 = fmaxf(m8, __shfl_xor(m8, 16, 64)); m8 = fmaxf(m8, __shfl_xor(m8, 32, 64));
            if (c < myC && quad == 0){
                sRedS[wv*304 + (c0 + c)*16 + li] = s8;
                sRedM[wv*304 + (c0 + c)*16 + li] = m8;
            }
        }
        __syncthreads();
        if (t < 608){
            int cc = t / 304, h = t - cc*304;     // cc: which column of the pair
            if (h < Hc){
                int ct = h >> 4;
                int cgf = (ct < 15) ? (ct/5) : 3;
                int w0 = (cgf << 2) + 2*cc;       // rg 2cc, 2cc+1 hold this column's rows
                float s = sRedS[w0*304 + h] + sRedS[(w0+1)*304 + h];
                float m = fmaxf(sRedM[w0*304 + h], sRedM[(w0+1)*304 + h]);
                float agg = s * (1.f/(1.f + expf(-m)));
                size_t o = (size_t)(bs0*64 + 2*mp0 + cc)*Hc + h;
                if constexpr (MODE == 0) aggb[o] += agg;   // message_atom += agg (sole owner)
                else                     aggb[o]  = agg;   // agg buffer
            }
        }
    }
}

// ---------------- ma += agg (tiny, float4)
__global__ __launch_bounds__(256) void k_ma_add(float* __restrict__ ma, const float* __restrict__ aggb){
    int i = blockIdx.x*256 + threadIdx.x;
    if (i < ROWS*Hc/4){
        float4 a = ((const float4*)aggb)[i];
        float4 v = ((float4*)ma)[i];
        v.x += a.x; v.y += a.y; v.z += a.z; v.w += a.w;
        ((float4*)ma)[i] = v;
    }
}

// ---------------- K3: agg (fallback final only)
__global__ __launch_bounds__(320) void k_agg(const float* __restrict__ message_bond,
        float* __restrict__ message_atom, float* __restrict__ agg_out, int final_mode){
    int t = threadIdx.x;
    int r = t / 80, c = t - r*80;
    if (c >= 75) return;
    int row = blockIdx.x*4 + r;
    int bs = row >> 6, m = row & 63;
    size_t base = ((size_t)(bs*Nc)*Nc + m)*(size_t)Hc + (size_t)c*4;
    float4 s  = {0.f, 0.f, 0.f, 0.f};
    float4 mx = {-INFINITY, -INFINITY, -INFINITY, -INFINITY};
    #pragma unroll 4
    for (int n = 0; n < Nc; ++n){
        float4 v = *(const float4*)(message_bond + base + (size_t)n*Nc*Hc);
        s.x += v.x; s.y += v.y; s.z += v.z; s.w += v.w;
        mx.x = fmaxf(mx.x, v.x); mx.y = fmaxf(mx.y, v.y);
        mx.z = fmaxf(mx.z, v.z); mx.w = fmaxf(mx.w, v.w);
    }
    float4 agg;
    agg.x = s.x * (1.f/(1.f + expf(-mx.x)));
    agg.y = s.y * (1.f/(1.f + expf(-mx.y)));
    agg.z = s.z * (1.f/(1.f + expf(-mx.z)));
    agg.w = s.w * (1.f/(1.f + expf(-mx.w)));
    size_t o = (size_t)row*Hc + (size_t)c*4;
    if (final_mode){
        *(float4*)(agg_out + o) = agg;
    } else {
        float4 cur = *(const float4*)(message_atom + o);
        cur.x += agg.x; cur.y += agg.y; cur.z += agg.z; cur.w += agg.w;
        *(float4*)(message_atom + o) = cur;
    }
}

// ---------------- K4: res[n,m] = dot(ma[n],ma[m])*adj[n,m]; sm = softmax over n per (b,s,m)
__global__ __launch_bounds__(256) void k_resonance_softmax(const float* __restrict__ message_atom,
        const float* __restrict__ adj, float* __restrict__ sm){
    int bs = blockIdx.x >> 6, m = blockIdx.x & 63;
    __shared__ float am[Hc];
    __shared__ float res[Nc];
    for (int d = threadIdx.x; d < Hc; d += blockDim.x)
        am[d] = message_atom[((size_t)(bs*Nc)+m)*Hc + d];
    __syncthreads();
    int wave = threadIdx.x >> 6, lane = threadIdx.x & 63;
    for (int n = wave; n < Nc; n += 4){
        const float* man = message_atom + ((size_t)(bs*Nc)+n)*Hc;
        float acc = 0.f;
        for (int d = lane; d < Hc; d += 64) acc = fmaf(man[d], am[d], acc);
        #pragma unroll
        for (int off = 32; off > 0; off >>= 1) acc += __shfl_xor(acc, off, 64);
        if (lane == 0) res[n] = acc * adj[((size_t)(bs*Nc)+n)*Nc + m];
    }
    __syncthreads();
    if (threadIdx.x < Nc){
        float v = res[threadIdx.x];
        float mx = v;
        #pragma unroll
        for (int off = 32; off > 0; off >>= 1) mx = fmaxf(mx, __shfl_xor(mx, off, 64));
        float e = expf(v - mx);
        float ssum = e;
        #pragma unroll
        for (int off = 32; off > 0; off >>= 1) ssum += __shfl_xor(ssum, off, 64);
        sm[((size_t)(bs*Nc)+threadIdx.x)*Nc + m] = e / ssum;
    }
}

// ---------------- K6: atom_hiddens = relu([agg|message_atom|input_atom] @ W_o + b_o)
#define R7 8
__global__ __launch_bounds__(320) void k_output(const float* __restrict__ agg,
        const float* __restrict__ message_atom, const float* __restrict__ input_atom,
        const float* __restrict__ W_o, const float* __restrict__ b_o, float* __restrict__ out){
    __shared__ float xin[R7][3*Hc];
    int r0 = blockIdx.x * R7;
    for (int idx = threadIdx.x; idx < R7*3*Hc; idx += blockDim.x){
        int r = idx / (3*Hc), k = idx - r*(3*Hc);
        int row = r0 + r;
        float v;
        if (k < Hc)           v = agg[(size_t)row*Hc + k];
        else if (k < 2*Hc)    v = message_atom[(size_t)row*Hc + (k - Hc)];
        else                  v = input_atom[(size_t)row*Hc + (k - 2*Hc)];
        xin[r][k] = v;
    }
    __syncthreads();
    int h = threadIdx.x;
    if (h < Hc){
        float acc[R7];
        #pragma unroll
        for (int r=0;r<R7;r++) acc[r] = b_o[h];
        for (int d = 0; d < 3*Hc; ++d){
            float w = W_o[d*Hc + h];
            #pragma unroll
            for (int r=0;r<R7;r++) acc[r] = fmaf(xin[r][d], w, acc[r]);
        }
        #pragma unroll
        for (int r=0;r<R7;r++) out[(size_t)(r0+r)*Hc + h] = reluf(acc[r]);
    }
}

extern "C" void kernel_launch(void* const* d_in, const int* in_sizes, int n_in,
                              void* d_out, int out_size, void* d_ws, size_t ws_size,
                              hipStream_t stream){
    const float* f_atoms  = (const float*)d_in[0];
    const float* f_bonds  = (const float*)d_in[1];
    const float* adj      = (const float*)d_in[2];
    const float* W_i_atom = (const float*)d_in[3];
    const float* W_i_bond = (const float*)d_in[4];
    const float* W_h0     = (const float*)d_in[5];
    const float* W_h1     = (const float*)d_in[6];
    const float* W_o      = (const float*)d_in[7];
    const float* b_o      = (const float*)d_in[8];

    float* out = (float*)d_out;
    float* atom_hiddens = out;                       // [2048, 300]
    float* mb_out = out + (size_t)ROWS*Hc;           // [131072, 300] fp32 (output #2)

    float* wsf = (float*)d_ws;
    float* input_atom   = wsf; wsf += (size_t)ROWS*Hc;
    float* message_atom = wsf; wsf += (size_t)ROWS*Hc;
    float* sm           = wsf; wsf += (size_t)EDGES;
    float* aggb         = wsf; wsf += (size_t)ROWS*Hc;          // fused agg buffer (2.4MB)
    float* ib           = wsf; wsf += (size_t)EDGES*Hc;         // 39.3M floats
    unsigned short* wsu = (unsigned short*)wsf;
    unsigned short* WP0 = wsu; wsu += 10*BSLICE;
    unsigned short* WP1 = wsu; wsu += 10*BSLICE;
    unsigned short* WPb = wsu; wsu += 5*BSLICE;

    size_t used = (size_t)((char*)wsu - (char*)d_ws);
    used = (used + 255) & ~(size_t)255;
    float* mbx = nullptr;
    if (ws_size >= used + (size_t)EDGES*Hc*sizeof(float))
        mbx = (float*)((char*)d_ws + used);          // step-1 output (157MB), enables oop step-2

    k_atom_embed<<<ROWS/RA, 320, 0, stream>>>(f_atoms, W_i_atom, input_atom, message_atom);
    k_prep_all<<<(25*BSLICE + 255)/256, 256, 0, stream>>>(W_h0, W_h1, W_i_bond, WP0);
    // bond embed (column-pair) + fused agg#1 (message_atom += agg)
    k_gemm_t<0><<<BS*32, 1024, 0, stream>>>(f_bonds, WPb, nullptr, adj, nullptr, nullptr, ib, message_atom);
    k_resonance_softmax<<<ROWS, 256, 0, stream>>>(message_atom, adj, sm);
    if (mbx){
        // step 1: ib -> mbx (out-of-place column-pair) + fused agg#2 -> aggb
        k_gemm_t<2><<<BS*32, 1024, 0, stream>>>(ib, WP0, message_atom, adj, sm, ib, mbx, aggb);
        k_ma_add<<<(ROWS*Hc/4 + 255)/256, 256, 0, stream>>>(message_atom, aggb);
        k_resonance_softmax<<<ROWS, 256, 0, stream>>>(message_atom, adj, sm);
        // step 2: mbx -> mb_out (out-of-place column-pair) + fused FINAL agg -> aggb
        k_gemm_t<2><<<BS*32, 1024, 0, stream>>>(mbx, WP1, message_atom, adj, sm, ib, mb_out, aggb);
        k_output<<<ROWS/R7, 320, 0, stream>>>(aggb, message_atom, input_atom, W_o, b_o, atom_hiddens);
    } else {
        // fallback (R3 path): step 1 -> mb_out, in-place closed-pair step 2, separate final agg
        float* agg_out = ib;   // alias: ib dead after step-2 GEMM
        k_gemm_t<2><<<BS*32, 1024, 0, stream>>>(ib, WP0, message_atom, adj, sm, ib, mb_out, aggb);
        k_ma_add<<<(ROWS*Hc/4 + 255)/256, 256, 0, stream>>>(message_atom, aggb);
        k_resonance_softmax<<<ROWS, 256, 0, stream>>>(message_atom, adj, sm);
        k_gemm_t<1><<<BS*32, 1024, 0, stream>>>(mb_out, WP1, message_atom, adj, sm, ib, mb_out, nullptr);
        k_agg<<<ROWS/4, 320, 0, stream>>>(mb_out, nullptr, agg_out, 1);
        k_output<<<ROWS/R7, 320, 0, stream>>>(agg_out, message_atom, input_atom, W_o, b_o, atom_hiddens);
    }
}

// Round 8
// 710.469 us; speedup vs baseline: 1.0908x; 1.0908x over previous
//
#include <hip/hip_runtime.h>
#include <hip/hip_bf16.h>
#include <math.h>

#define Bc 8
#define Sc 4
#define Nc 64
#define AF 133
#define BFD 147
#define Hc 300
#define BS (Bc*Sc)                  // 32
#define ROWS (BS*Nc)                // 2048 atom rows
#define EDGES (BS*Nc*Nc)            // 131072 edges
#define BSLICE 19456                // shorts per kt-slice of WP: 2*19*64*8
#define BHALF  9728                 // 19*64*8

typedef float f32x4 __attribute__((ext_vector_type(4)));
typedef short bf16x8 __attribute__((ext_vector_type(8)));
typedef float f32x4v __attribute__((ext_vector_type(4)));
typedef f32x4v f32x4u __attribute__((aligned(4)));   // 4B-aligned float4 (f_bonds rows are 588B)
struct us4 { unsigned short x, y, z, w; } __attribute__((aligned(8)));
union U4 { uint4 u; bf16x8 v; };

__device__ __forceinline__ float reluf(float x){ return fmaxf(x, 0.f); }
__device__ __forceinline__ float b2f(unsigned short u){ union{unsigned int i;float f;}v; v.i = ((unsigned int)u)<<16; return v.f; }
__device__ __forceinline__ unsigned short f2b(float f){ __hip_bfloat16 h = __float2bfloat16(f); return *reinterpret_cast<unsigned short*>(&h); }
__device__ __forceinline__ void split2(float x, unsigned short &hi, unsigned short &lo){
    unsigned short h = f2b(x);
    float r = x - b2f(h);
    hi = h; lo = f2b(r);
}

typedef __attribute__((address_space(1))) const unsigned int* gas1_t;
typedef __attribute__((address_space(3))) unsigned int* las3_t;
__device__ __forceinline__ void gload_lds16(const void* g, void* l){
    __builtin_amdgcn_global_load_lds((gas1_t)g, (las3_t)l, 16, 0, 0);
}

// raw barrier, no counter drain (A-prefetch stays in flight across it)
__device__ __forceinline__ void bar_only(){
    __builtin_amdgcn_sched_barrier(0);
    asm volatile("" ::: "memory");
    __builtin_amdgcn_s_barrier();
    asm volatile("" ::: "memory");
    __builtin_amdgcn_sched_barrier(0);
}
// barrier draining vm (copyB gload_lds) + lgkm (buildA ds_writes) only
__device__ __forceinline__ void bar_drain(){
    __builtin_amdgcn_sched_barrier(0);
    asm volatile("s_waitcnt vmcnt(0) lgkmcnt(0)" ::: "memory");
    __builtin_amdgcn_s_barrier();
    asm volatile("" ::: "memory");
    __builtin_amdgcn_sched_barrier(0);
}

// ---------------- K1: input_atom = relu(f_atoms @ W_i_atom); message_atom = copy (fp32 VALU)
__global__ __launch_bounds__(320) void k_atom_embed(const float* __restrict__ f_atoms,
        const float* __restrict__ W, float* __restrict__ input_atom, float* __restrict__ message_atom){
    __shared__ float x[AF];
    int row = blockIdx.x;
    const float* fr = f_atoms + (size_t)row*AF;
    for (int d = threadIdx.x; d < AF; d += blockDim.x) x[d] = fr[d];
    __syncthreads();
    int h = threadIdx.x;
    if (h < Hc){
        float acc = 0.f;
        for (int d = 0; d < AF; ++d) acc = fmaf(x[d], W[d*Hc + h], acc);
        float v = reluf(acc);
        input_atom[(size_t)row*Hc + h] = v;
        message_atom[(size_t)row*Hc + h] = v;
    }
}

// ---------------- prep: W [K][300] -> split bf16, layout [kt][hi/lo][19 ct][64 lane][8]
__global__ __launch_bounds__(256) void k_prep_wp2(const float* __restrict__ W, int K, int NKT,
        unsigned short* __restrict__ WP){
    int idx = blockIdx.x*256 + threadIdx.x;
    if (idx >= NKT*BSLICE) return;
    int j  = idx & 7;
    int l  = (idx >> 3) & 63;
    int ct = (idx >> 9) % 19;
    int rem = idx / BHALF;
    int hl = rem & 1;
    int kt = rem >> 1;
    int col = ct*16 + (l & 15);
    int k   = kt*32 + (l >> 4)*8 + j;
    float v = (col < Hc && k < K) ? W[k*Hc + col] : 0.f;
    unsigned short hi, lo; split2(v, hi, lo);
    WP[idx] = hl ? lo : hi;
}

// ---------------- tiled split-bf16 MFMA edge GEMM (128 rows x 304 cols per block)
// MODE 0: column-pair blocks: ib = relu((adj*f_bonds)@W_i_bond) + fused agg (+= message_atom)
// MODE 2: column-pair blocks, out-of-place: dst = relu(ib + A@W_h)*sm + fused agg -> aggb (=)
//         A-row for output (n,m): adj[(m,n)]*ma[n] - mb_old[(m,n)]  (contiguous row reads)
// MODE 1: closed-pair blocks, in-place (fallback), no agg fusion
// ABF: A-source (mb_old) stored as plain bf16 (step-2). DBF: dst stored as plain bf16 (step-1).
// bf16 mb_old only drops the lo-term of -mb_old in the split-bf16 MFMA (error ~2^-9 rel);
// all fused aggs use pre-rounding fp32 accumulators.
template<int MODE, int ABF, int DBF>
__global__ __launch_bounds__(1024) void k_gemm_t(
        const float* __restrict__ Asrc,          // M0: f_bonds [E][147]; M1/M2: mb_old [E][300] (fp32 or bf16 if ABF)
        const unsigned short* __restrict__ WP,   // [NKT][2][19][64][8]
        const float* __restrict__ ma,
        const float* __restrict__ adj,
        const float* __restrict__ sm,
        const float* __restrict__ ib,
        float* __restrict__ dst,                 // bf16 plane if DBF
        float* __restrict__ aggb)                // M0: message_atom (+=); M2: agg buffer (=)
{
    constexpr int NKT  = (MODE != 0) ? 10 : 5;
    constexpr int ASTR = (MODE != 0) ? 300 : BFD;

    __shared__ unsigned short sAhi[4096];        // 128 rows x 32 k (chunked)
    __shared__ unsigned short sAlo[4096];
    __shared__ unsigned short sB[BSLICE];        // hi block then lo block
    __shared__ int s_eOut[128];
    __shared__ int s_eRev[128];
    __shared__ float s_adjRev[128];
    __shared__ int s_aAtom[128];

    const int t = threadIdx.x;
    const int bs0 = blockIdx.x >> 5;             // MODE0/2: (b,s) slab
    const int mp0 = blockIdx.x & 31;             // MODE0/2: column pair (m0=2*mp0, m1=m0+1)

    if constexpr (MODE == 1){
        if (t < 128){
            int r = t;
            int bs = bs0, kk = mp0;
            int s1 = 64-kk, s2 = 127-2*kk, s3 = 128-kk;
            int a, b;
            if (r < s1){ a = kk; b = kk + r; }
            else if (r < s2){ a = kk+1 + (r - s1); b = kk; }
            else if (r < s3){ a = 63-kk; b = 63-kk + (r - s2); }
            else { a = 64-kk + (r - s3); b = 63-kk; }
            int eo = (bs*64 + a)*64 + b;
            int er = (bs*64 + b)*64 + a;
            s_eOut[r] = eo; s_eRev[r] = er; s_aAtom[r] = bs*64 + a;
            s_adjRev[r] = adj[er];
        }
        __syncthreads();
    }

    // ---- A-build role: thread t -> row brow, k-offset koff (4 floats), LDS shorts [4t..4t+3]
    const int rt_b = t >> 7;
    const int q_b  = (t >> 5) & 3;
    const int li_b = (t >> 1) & 15;
    const int half = t & 1;
    const int brow = rt_b*16 + li_b;
    const int koff = q_b*8 + 4*half;
    const float* aRow = nullptr;
    const unsigned short* aRowH = nullptr;
    const float* mRow = nullptr;
    float adjR = 0.f;
    if constexpr (MODE == 1){
        aRow = Asrc + (size_t)s_eRev[brow]*ASTR;
        mRow = ma + (size_t)s_aAtom[brow]*Hc;
        adjR = s_adjRev[brow];
    } else if constexpr (MODE == 2){
        int n = brow & 63, cc = brow >> 6;
        int eR = (bs0*64 + (2*mp0 + cc))*64 + n;       // row (m,n): contiguous per cc
        if constexpr (ABF) aRowH = (const unsigned short*)Asrc + (size_t)eR*ASTR;
        else               aRow  = Asrc + (size_t)eR*ASTR;
        mRow = ma + (size_t)(bs0*64 + n)*Hc;
        adjR = adj[eR];
    } else {
        int n = brow & 63, cc = brow >> 6;
        int e = (bs0*64 + n)*64 + (2*mp0 + cc);        // output edge itself
        aRow = Asrc + (size_t)e*ASTR;
        adjR = adj[e];
    }

    float pm[4], pa[4];
    auto prefetchA = [&](int kt){
        int k0 = kt*32 + koff;
        if constexpr (MODE != 0){
            if (k0 <= 296){
                if constexpr (ABF){
                    us4 v = *(const us4*)(aRowH + k0);     // 8B aligned (row pitch 600B, k0%4==0)
                    pm[0]=b2f(v.x); pm[1]=b2f(v.y); pm[2]=b2f(v.z); pm[3]=b2f(v.w);
                } else {
                    float4 v = *(const float4*)(aRow + k0);
                    pm[0]=v.x; pm[1]=v.y; pm[2]=v.z; pm[3]=v.w;
                }
                float4 w = *(const float4*)(mRow + k0);
                pa[0]=w.x; pa[1]=w.y; pa[2]=w.z; pa[3]=w.w;
            }
        } else {
            if (k0 + 3 < BFD){
                f32x4u v = *(const f32x4u*)(aRow + k0);   // 4B-aligned dwordx4
                pm[0]=v.x; pm[1]=v.y; pm[2]=v.z; pm[3]=v.w;
            } else {
                #pragma unroll
                for (int j = 0; j < 4; ++j){
                    int k = k0 + j;
                    pm[j] = (k < BFD) ? aRow[k] : 0.f;
                }
            }
        }
    };
    auto buildA = [&](int kt){
        int k0 = kt*32 + koff;
        float xv[4];
        if constexpr (MODE != 0){
            if (k0 <= 296){
                #pragma unroll
                for (int j = 0; j < 4; ++j) xv[j] = fmaf(adjR, pa[j], -pm[j]);
            } else { xv[0]=xv[1]=xv[2]=xv[3]=0.f; }
        } else {
            #pragma unroll
            for (int j = 0; j < 4; ++j) xv[j] = adjR * pm[j];
        }
        unsigned short h0,l0,h1,l1,h2,l2,h3,l3;
        split2(xv[0],h0,l0); split2(xv[1],h1,l1);
        split2(xv[2],h2,l2); split2(xv[3],h3,l3);
        uint2 hw, lw;
        hw.x = (unsigned int)h0 | ((unsigned int)h1<<16);
        hw.y = (unsigned int)h2 | ((unsigned int)h3<<16);
        lw.x = (unsigned int)l0 | ((unsigned int)l1<<16);
        lw.y = (unsigned int)l2 | ((unsigned int)l3<<16);
        *(uint2*)&sAhi[4*t] = hw;        // byte 8t: bank-linear, conflict-free
        *(uint2*)&sAlo[4*t] = lw;
    };
    auto copyB = [&](int kt){
        const unsigned short* src = WP + (size_t)kt*BSLICE;
        #pragma unroll
        for (int rep = 0; rep < 3; ++rep){
            int i = t + rep*1024;
            if (i < BSLICE/8)
                gload_lds16(src + (size_t)i*8, &sB[i*8]);
        }
    };

    // ---- compute role
    const int wv = t >> 6, lane = t & 63;
    const int li = lane & 15, quad = lane >> 4;
    const int rg = wv & 3;                       // row-tiles 2rg, 2rg+1
    const int cg = wv >> 2;
    const int c0 = cg*5;
    const int myC = (cg < 3) ? 5 : 4;

    f32x4 acc[5][2];
    #pragma unroll
    for (int c = 0; c < 5; ++c){ acc[c][0] = (f32x4){0,0,0,0}; acc[c][1] = (f32x4){0,0,0,0}; }

    prefetchA(0);

    // MODE1/2: preload ib into acc (epilogue loads vanish; overlaps kt0 staging)
    if constexpr (MODE != 0){
        #pragma unroll
        for (int c = 0; c < 5; ++c){
            if (c < myC){
                int h = (c0 + c)*16 + li;
                if (h < Hc){
                    #pragma unroll
                    for (int r2 = 0; r2 < 2; ++r2)
                        #pragma unroll
                        for (int i = 0; i < 4; ++i){
                            int row = (2*rg + r2)*16 + quad*4 + i;
                            int e;
                            if constexpr (MODE == 1) e = s_eOut[row];
                            else e = (bs0*64 + (row & 63))*64 + (2*mp0 + (row >> 6));
                            acc[c][r2][i] = ib[(size_t)e*Hc + h];
                        }
                }
            }
        }
    }

    for (int kt = 0; kt < NKT; ++kt){
        if (kt) bar_only();                      // B1: pure barrier (prefetchA stays in flight)
        copyB(kt);                               // 3 async gload_lds (L2-hot)
        buildA(kt);                              // consumes pm/pa (compiler-counted vmcnt)
        bar_drain();                             // vmcnt(0)+lgkm(0): copyB + sA writes visible
        if (kt+1 < NKT) prefetchA(kt+1);         // HBM latency spans full compute(kt) + B1
        __builtin_amdgcn_s_setprio(1);
        U4 a0h, a0l, a1h, a1l;
        a0h.u = *(const uint4*)&sAhi[((2*rg  )*64 + lane)*8];
        a0l.u = *(const uint4*)&sAlo[((2*rg  )*64 + lane)*8];
        a1h.u = *(const uint4*)&sAhi[((2*rg+1)*64 + lane)*8];
        a1l.u = *(const uint4*)&sAlo[((2*rg+1)*64 + lane)*8];
        #pragma unroll
        for (int c = 0; c < 5; ++c){
            if (c < myC){
                U4 bh, bl;
                bh.u = *(const uint4*)&sB[        (c0+c)*512 + lane*8];
                bl.u = *(const uint4*)&sB[BHALF + (c0+c)*512 + lane*8];
                acc[c][0] = __builtin_amdgcn_mfma_f32_16x16x32_bf16(a0h.v, bl.v, acc[c][0], 0,0,0);
                acc[c][0] = __builtin_amdgcn_mfma_f32_16x16x32_bf16(a0l.v, bh.v, acc[c][0], 0,0,0);
                acc[c][0] = __builtin_amdgcn_mfma_f32_16x16x32_bf16(a0h.v, bh.v, acc[c][0], 0,0,0);
                acc[c][1] = __builtin_amdgcn_mfma_f32_16x16x32_bf16(a1h.v, bl.v, acc[c][1], 0,0,0);
                acc[c][1] = __builtin_amdgcn_mfma_f32_16x16x32_bf16(a1l.v, bh.v, acc[c][1], 0,0,0);
                acc[c][1] = __builtin_amdgcn_mfma_f32_16x16x32_bf16(a1h.v, bh.v, acc[c][1], 0,0,0);
            }
        }
        __builtin_amdgcn_s_setprio(0);
    }

    if constexpr (MODE == 1){
        // ---- closed-pair epilogue: stores only
        int eO[2][4]; float smv[2][4];
        #pragma unroll
        for (int r2 = 0; r2 < 2; ++r2)
            #pragma unroll
            for (int i = 0; i < 4; ++i){
                int row = (2*rg + r2)*16 + quad*4 + i;
                int e = s_eOut[row];
                eO[r2][i] = e;
                smv[r2][i] = sm[e];
            }
        #pragma unroll
        for (int c = 0; c < 5; ++c){
            if (c >= myC) continue;
            int h = (c0 + c)*16 + li;
            if (h >= Hc) continue;
            #pragma unroll
            for (int r2 = 0; r2 < 2; ++r2)
                #pragma unroll
                for (int i = 0; i < 4; ++i){
                    size_t off = (size_t)eO[r2][i]*Hc + h;
                    dst[off] = reluf(acc[c][r2][i]) * smv[r2][i];
                }
        }
    } else {
        // ---- column-pair epilogue: store + fused column reduction (agg)
        __syncthreads();                          // all sB reads done -> reuse sB as sRed
        float* sRedS = (float*)sB;                // [16 waves][304]
        float* sRedM = sRedS + 16*304;
        int eO[2][4]; float smv[2][4];
        #pragma unroll
        for (int r2 = 0; r2 < 2; ++r2)
            #pragma unroll
            for (int i = 0; i < 4; ++i){
                int row = (2*rg + r2)*16 + quad*4 + i;
                int e = (bs0*64 + (row & 63))*64 + (2*mp0 + (row >> 6));
                eO[r2][i] = e;
                if constexpr (MODE == 2) smv[r2][i] = sm[e];
            }
        #pragma unroll
        for (int c = 0; c < 5; ++c){
            float s8 = 0.f, m8 = -INFINITY;
            int h = (c0 + c)*16 + li;
            if (c < myC && h < Hc){
                #pragma unroll
                for (int r2 = 0; r2 < 2; ++r2)
                    #pragma unroll
                    for (int i = 0; i < 4; ++i){
                        float v = reluf(acc[c][r2][i]);
                        if constexpr (MODE == 2) v *= smv[r2][i];
                        if constexpr (DBF)
                            ((unsigned short*)dst)[(size_t)eO[r2][i]*Hc + h] = f2b(v);
                        else
                            dst[(size_t)eO[r2][i]*Hc + h] = v;
                        s8 += v; m8 = fmaxf(m8, v);
                    }
            }
            // butterfly across quads (lane bits 4,5): 32-row partial per (wave, h)
            s8 += __shfl_xor(s8, 16, 64); s8 += __shfl_xor(s8, 32, 64);
            m8 = fmaxf(m8, __shfl_xor(m8, 16, 64)); m8 = fmaxf(m8, __shfl_xor(m8, 32, 64));
            if (c < myC && quad == 0){
                sRedS[wv*304 + (c0 + c)*16 + li] = s8;
                sRedM[wv*304 + (c0 + c)*16 + li] = m8;
            }
        }
        __syncthreads();
        if (t < 608){
            int cc = t / 304, h = t - cc*304;     // cc: which column of the pair
            if (h < Hc){
                int ct = h >> 4;
                int cgf = (ct < 15) ? (ct/5) : 3;
                int w0 = (cgf << 2) + 2*cc;       // rg 2cc, 2cc+1 hold this column's rows
                float s = sRedS[w0*304 + h] + sRedS[(w0+1)*304 + h];
                float m = fmaxf(sRedM[w0*304 + h], sRedM[(w0+1)*304 + h]);
                float agg = s * (1.f/(1.f + expf(-m)));
                size_t o = (size_t)(bs0*64 + 2*mp0 + cc)*Hc + h;
                if constexpr (MODE == 0) aggb[o] += agg;   // message_atom += agg (sole owner)
                else                     aggb[o]  = agg;   // agg buffer
            }
        }
    }
}

// ---------------- ma += agg (tiny, float4)
__global__ __launch_bounds__(256) void k_ma_add(float* __restrict__ ma, const float* __restrict__ aggb){
    int i = blockIdx.x*256 + threadIdx.x;
    if (i < ROWS*Hc/4){
        float4 a = ((const float4*)aggb)[i];
        float4 v = ((float4*)ma)[i];
        v.x += a.x; v.y += a.y; v.z += a.z; v.w += a.w;
        ((float4*)ma)[i] = v;
    }
}

// ---------------- K3: agg (fallback final only)
__global__ __launch_bounds__(320) void k_agg(const float* __restrict__ message_bond,
        float* __restrict__ message_atom, float* __restrict__ agg_out, int final_mode){
    int t = threadIdx.x;
    int r = t / 80, c = t - r*80;
    if (c >= 75) return;
    int row = blockIdx.x*4 + r;
    int bs = row >> 6, m = row & 63;
    size_t base = ((size_t)(bs*Nc)*Nc + m)*(size_t)Hc + (size_t)c*4;
    float4 s  = {0.f, 0.f, 0.f, 0.f};
    float4 mx = {-INFINITY, -INFINITY, -INFINITY, -INFINITY};
    #pragma unroll 4
    for (int n = 0; n < Nc; ++n){
        float4 v = *(const float4*)(message_bond + base + (size_t)n*Nc*Hc);
        s.x += v.x; s.y += v.y; s.z += v.z; s.w += v.w;
        mx.x = fmaxf(mx.x, v.x); mx.y = fmaxf(mx.y, v.y);
        mx.z = fmaxf(mx.z, v.z); mx.w = fmaxf(mx.w, v.w);
    }
    float4 agg;
    agg.x = s.x * (1.f/(1.f + expf(-mx.x)));
    agg.y = s.y * (1.f/(1.f + expf(-mx.y)));
    agg.z = s.z * (1.f/(1.f + expf(-mx.z)));
    agg.w = s.w * (1.f/(1.f + expf(-mx.w)));
    size_t o = (size_t)row*Hc + (size_t)c*4;
    if (final_mode){
        *(float4*)(agg_out + o) = agg;
    } else {
        float4 cur = *(const float4*)(message_atom + o);
        cur.x += agg.x; cur.y += agg.y; cur.z += agg.z; cur.w += agg.w;
        *(float4*)(message_atom + o) = cur;
    }
}

// ---------------- K4: res[n,m] = dot(ma[n],ma[m])*adj[n,m]; sm = softmax over n per (b,s,m)
__global__ __launch_bounds__(256) void k_resonance_softmax(const float* __restrict__ message_atom,
        const float* __restrict__ adj, float* __restrict__ sm){
    int bs = blockIdx.x >> 6, m = blockIdx.x & 63;
    __shared__ float am[Hc];
    __shared__ float res[Nc];
    for (int d = threadIdx.x; d < Hc; d += blockDim.x)
        am[d] = message_atom[((size_t)(bs*Nc)+m)*Hc + d];
    __syncthreads();
    int wave = threadIdx.x >> 6, lane = threadIdx.x & 63;
    for (int n = wave; n < Nc; n += 4){
        const float* man = message_atom + ((size_t)(bs*Nc)+n)*Hc;
        float acc = 0.f;
        for (int d = lane; d < Hc; d += 64) acc = fmaf(man[d], am[d], acc);
        #pragma unroll
        for (int off = 32; off > 0; off >>= 1) acc += __shfl_xor(acc, off, 64);
        if (lane == 0) res[n] = acc * adj[((size_t)(bs*Nc)+n)*Nc + m];
    }
    __syncthreads();
    if (threadIdx.x < Nc){
        float v = res[threadIdx.x];
        float mx = v;
        #pragma unroll
        for (int off = 32; off > 0; off >>= 1) mx = fmaxf(mx, __shfl_xor(mx, off, 64));
        float e = expf(v - mx);
        float ssum = e;
        #pragma unroll
        for (int off = 32; off > 0; off >>= 1) ssum += __shfl_xor(ssum, off, 64);
        sm[((size_t)(bs*Nc)+threadIdx.x)*Nc + m] = e / ssum;
    }
}

// ---------------- K6: atom_hiddens = relu([agg|message_atom|input_atom] @ W_o + b_o)
#define R7 4
__global__ __launch_bounds__(320) void k_output(const float* __restrict__ agg,
        const float* __restrict__ message_atom, const float* __restrict__ input_atom,
        const float* __restrict__ W_o, const float* __restrict__ b_o, float* __restrict__ out){
    __shared__ float xin[R7][3*Hc];
    int r0 = blockIdx.x * R7;
    for (int idx = threadIdx.x; idx < R7*3*Hc; idx += blockDim.x){
        int r = idx / (3*Hc), k = idx - r*(3*Hc);
        int row = r0 + r;
        float v;
        if (k < Hc)           v = agg[(size_t)row*Hc + k];
        else if (k < 2*Hc)    v = message_atom[(size_t)row*Hc + (k - Hc)];
        else                  v = input_atom[(size_t)row*Hc + (k - 2*Hc)];
        xin[r][k] = v;
    }
    __syncthreads();
    int h = threadIdx.x;
    if (h < Hc){
        float acc[R7];
        #pragma unroll
        for (int r=0;r<R7;r++) acc[r] = b_o[h];
        for (int d = 0; d < 3*Hc; ++d){
            float w = W_o[d*Hc + h];
            #pragma unroll
            for (int r=0;r<R7;r++) acc[r] = fmaf(xin[r][d], w, acc[r]);
        }
        #pragma unroll
        for (int r=0;r<R7;r++) out[(size_t)(r0+r)*Hc + h] = reluf(acc[r]);
    }
}

extern "C" void kernel_launch(void* const* d_in, const int* in_sizes, int n_in,
                              void* d_out, int out_size, void* d_ws, size_t ws_size,
                              hipStream_t stream){
    const float* f_atoms  = (const float*)d_in[0];
    const float* f_bonds  = (const float*)d_in[1];
    const float* adj      = (const float*)d_in[2];
    const float* W_i_atom = (const float*)d_in[3];
    const float* W_i_bond = (const float*)d_in[4];
    const float* W_h0     = (const float*)d_in[5];
    const float* W_h1     = (const float*)d_in[6];
    const float* W_o      = (const float*)d_in[7];
    const float* b_o      = (const float*)d_in[8];

    float* out = (float*)d_out;
    float* atom_hiddens = out;                       // [2048, 300]
    float* mb_out = out + (size_t)ROWS*Hc;           // [131072, 300] fp32 (output #2)

    float* wsf = (float*)d_ws;
    float* input_atom   = wsf; wsf += (size_t)ROWS*Hc;
    float* message_atom = wsf; wsf += (size_t)ROWS*Hc;
    float* sm           = wsf; wsf += (size_t)EDGES;
    float* aggb         = wsf; wsf += (size_t)ROWS*Hc;          // fused agg buffer (2.4MB)
    float* ib           = wsf; wsf += (size_t)EDGES*Hc;         // 39.3M floats
    unsigned short* wsu = (unsigned short*)wsf;
    unsigned short* WP0 = wsu; wsu += 10*BSLICE;
    unsigned short* WP1 = wsu; wsu += 10*BSLICE;
    unsigned short* WPb = wsu; wsu += 5*BSLICE;

    size_t used = (size_t)((char*)wsu - (char*)d_ws);
    used = (used + 255) & ~(size_t)255;
    unsigned short* mbx = nullptr;                   // step-1 output, bf16 (78.6MB)
    if (ws_size >= used + (size_t)EDGES*Hc*sizeof(unsigned short))
        mbx = (unsigned short*)((char*)d_ws + used);

    k_atom_embed<<<ROWS, 320, 0, stream>>>(f_atoms, W_i_atom, input_atom, message_atom);
    k_prep_wp2<<<(10*BSLICE + 255)/256, 256, 0, stream>>>(W_h0, Hc, 10, WP0);
    k_prep_wp2<<<(10*BSLICE + 255)/256, 256, 0, stream>>>(W_h1, Hc, 10, WP1);
    k_prep_wp2<<<(5*BSLICE + 255)/256, 256, 0, stream>>>(W_i_bond, BFD, 5, WPb);
    // bond embed (column-pair) + fused agg#1 (message_atom += agg)
    k_gemm_t<0,0,0><<<BS*32, 1024, 0, stream>>>(f_bonds, WPb, nullptr, adj, nullptr, nullptr, ib, message_atom);
    k_resonance_softmax<<<ROWS, 256, 0, stream>>>(message_atom, adj, sm);
    if (mbx){
        // step 1: ib -> mbx (bf16, out-of-place column-pair) + fused agg#2 -> aggb
        k_gemm_t<2,0,1><<<BS*32, 1024, 0, stream>>>(ib, WP0, message_atom, adj, sm, ib, (float*)mbx, aggb);
        k_ma_add<<<(ROWS*Hc/4 + 255)/256, 256, 0, stream>>>(message_atom, aggb);
        k_resonance_softmax<<<ROWS, 256, 0, stream>>>(message_atom, adj, sm);
        // step 2: mbx (bf16 A) -> mb_out (fp32, out-of-place column-pair) + fused FINAL agg -> aggb
        k_gemm_t<2,1,0><<<BS*32, 1024, 0, stream>>>((const float*)mbx, WP1, message_atom, adj, sm, ib, mb_out, aggb);
        k_output<<<ROWS/R7, 320, 0, stream>>>(aggb, message_atom, input_atom, W_o, b_o, atom_hiddens);
    } else {
        // fallback (R3 path): step 1 -> mb_out, in-place closed-pair step 2, separate final agg
        float* agg_out = ib;   // alias: ib dead after step-2 GEMM
        k_gemm_t<2,0,0><<<BS*32, 1024, 0, stream>>>(ib, WP0, message_atom, adj, sm, ib, mb_out, aggb);
        k_ma_add<<<(ROWS*Hc/4 + 255)/256, 256, 0, stream>>>(message_atom, aggb);
        k_resonance_softmax<<<ROWS, 256, 0, stream>>>(message_atom, adj, sm);
        k_gemm_t<1,0,0><<<BS*32, 1024, 0, stream>>>(mb_out, WP1, message_atom, adj, sm, ib, mb_out, nullptr);
        k_agg<<<ROWS/4, 320, 0, stream>>>(mb_out, nullptr, agg_out, 1);
        k_output<<<ROWS/R7, 320, 0, stream>>>(agg_out, message_atom, input_atom, W_o, b_o, atom_hiddens);
    }
}

// Round 9
// 669.481 us; speedup vs baseline: 1.1576x; 1.0612x over previous
//
#include <hip/hip_runtime.h>
#include <hip/hip_bf16.h>
#include <math.h>

#define Bc 8
#define Sc 4
#define Nc 64
#define AF 133
#define BFD 147
#define Hc 300
#define BS (Bc*Sc)                  // 32
#define ROWS (BS*Nc)                // 2048 atom rows
#define EDGES (BS*Nc*Nc)            // 131072 edges
#define BSLICE 19456                // shorts per kt-slice of WP: 2*19*64*8
#define BHALF  9728                 // 19*64*8

typedef float f32x4 __attribute__((ext_vector_type(4)));
typedef short bf16x8 __attribute__((ext_vector_type(8)));
typedef float f32x4v __attribute__((ext_vector_type(4)));
typedef f32x4v f32x4u __attribute__((aligned(4)));   // 4B-aligned float4 (f_bonds rows are 588B)
struct us4 { unsigned short x, y, z, w; } __attribute__((aligned(8)));
union U4 { uint4 u; bf16x8 v; };

__device__ __forceinline__ float reluf(float x){ return fmaxf(x, 0.f); }
__device__ __forceinline__ float b2f(unsigned short u){ union{unsigned int i;float f;}v; v.i = ((unsigned int)u)<<16; return v.f; }
__device__ __forceinline__ unsigned short f2b(float f){ __hip_bfloat16 h = __float2bfloat16(f); return *reinterpret_cast<unsigned short*>(&h); }
__device__ __forceinline__ void split2(float x, unsigned short &hi, unsigned short &lo){
    unsigned short h = f2b(x);
    float r = x - b2f(h);
    hi = h; lo = f2b(r);
}

typedef __attribute__((address_space(1))) const unsigned int* gas1_t;
typedef __attribute__((address_space(3))) unsigned int* las3_t;
__device__ __forceinline__ void gload_lds16(const void* g, void* l){
    __builtin_amdgcn_global_load_lds((gas1_t)g, (las3_t)l, 16, 0, 0);
}

// raw barrier, no counter drain (A-prefetch stays in flight across it)
__device__ __forceinline__ void bar_only(){
    __builtin_amdgcn_sched_barrier(0);
    asm volatile("" ::: "memory");
    __builtin_amdgcn_s_barrier();
    asm volatile("" ::: "memory");
    __builtin_amdgcn_sched_barrier(0);
}
// barrier draining vm (copyB gload_lds) + lgkm (buildA ds_writes) only
__device__ __forceinline__ void bar_drain(){
    __builtin_amdgcn_sched_barrier(0);
    asm volatile("s_waitcnt vmcnt(0) lgkmcnt(0)" ::: "memory");
    __builtin_amdgcn_s_barrier();
    asm volatile("" ::: "memory");
    __builtin_amdgcn_sched_barrier(0);
}

// ---------------- K1: input_atom = relu(f_atoms @ W_i_atom); message_atom = copy (fp32 VALU)
__global__ __launch_bounds__(320) void k_atom_embed(const float* __restrict__ f_atoms,
        const float* __restrict__ W, float* __restrict__ input_atom, float* __restrict__ message_atom){
    __shared__ float x[AF];
    int row = blockIdx.x;
    const float* fr = f_atoms + (size_t)row*AF;
    for (int d = threadIdx.x; d < AF; d += blockDim.x) x[d] = fr[d];
    __syncthreads();
    int h = threadIdx.x;
    if (h < Hc){
        float acc = 0.f;
        for (int d = 0; d < AF; ++d) acc = fmaf(x[d], W[d*Hc + h], acc);
        float v = reluf(acc);
        input_atom[(size_t)row*Hc + h] = v;
        message_atom[(size_t)row*Hc + h] = v;
    }
}

// ---------------- prep: W [K][300] -> split bf16, layout [kt][hi/lo][19 ct][64 lane][8]
__global__ __launch_bounds__(256) void k_prep_wp2(const float* __restrict__ W, int K, int NKT,
        unsigned short* __restrict__ WP){
    int idx = blockIdx.x*256 + threadIdx.x;
    if (idx >= NKT*BSLICE) return;
    int j  = idx & 7;
    int l  = (idx >> 3) & 63;
    int ct = (idx >> 9) % 19;
    int rem = idx / BHALF;
    int hl = rem & 1;
    int kt = rem >> 1;
    int col = ct*16 + (l & 15);
    int k   = kt*32 + (l >> 4)*8 + j;
    float v = (col < Hc && k < K) ? W[k*Hc + col] : 0.f;
    unsigned short hi, lo; split2(v, hi, lo);
    WP[idx] = hl ? lo : hi;
}

// ---------------- tiled split-bf16 MFMA edge GEMM (128 rows x 304 cols per block)
// MODE 0: column-pair blocks: ib = relu((adj*f_bonds)@W_i_bond) + fused agg (+= message_atom)
// MODE 2: column-pair blocks, out-of-place: dst = relu(ib + A@W_h)*sm + fused agg -> aggb (=)
//         A-row for output (n,m): adj[(m,n)]*ma[n] - mb_old[(m,n)]  (contiguous row reads)
// MODE 1: closed-pair blocks, in-place (fallback), no agg fusion
// ABF: A-source (mb_old) is bf16. DBF: dst stored bf16. IBF: C-init (ib) read as bf16.
// bf16 A only drops the lo-term of -mb_old in the split-bf16 MFMA (~2^-9 rel); bf16 C-init
// adds <=0.004*|ib| once per output (not compounded: same rounded value used by both steps).
// All fused aggs reduce pre-rounding fp32 accumulators.
template<int MODE, int ABF, int DBF, int IBF>
__global__ __launch_bounds__(1024) void k_gemm_t(
        const float* __restrict__ Asrc,          // M0: f_bonds [E][147]; M1/M2: mb_old [E][300] (bf16 if ABF)
        const unsigned short* __restrict__ WP,   // [NKT][2][19][64][8]
        const float* __restrict__ ma,
        const float* __restrict__ adj,
        const float* __restrict__ sm,
        const float* __restrict__ ib,            // bf16 plane if IBF
        float* __restrict__ dst,                 // bf16 plane if DBF
        float* __restrict__ aggb)                // M0: message_atom (+=); M2: agg buffer (=)
{
    constexpr int NKT  = (MODE != 0) ? 10 : 5;
    constexpr int ASTR = (MODE != 0) ? 300 : BFD;

    __shared__ unsigned short sAhi[4096];        // 128 rows x 32 k (chunked)
    __shared__ unsigned short sAlo[4096];
    __shared__ unsigned short sB[BSLICE];        // hi block then lo block
    __shared__ int s_eOut[128];
    __shared__ int s_eRev[128];
    __shared__ float s_adjRev[128];
    __shared__ int s_aAtom[128];

    const int t = threadIdx.x;
    const int bs0 = blockIdx.x >> 5;             // MODE0/2: (b,s) slab
    const int mp0 = blockIdx.x & 31;             // MODE0/2: column pair (m0=2*mp0, m1=m0+1)

    if constexpr (MODE == 1){
        if (t < 128){
            int r = t;
            int bs = bs0, kk = mp0;
            int s1 = 64-kk, s2 = 127-2*kk, s3 = 128-kk;
            int a, b;
            if (r < s1){ a = kk; b = kk + r; }
            else if (r < s2){ a = kk+1 + (r - s1); b = kk; }
            else if (r < s3){ a = 63-kk; b = 63-kk + (r - s2); }
            else { a = 64-kk + (r - s3); b = 63-kk; }
            int eo = (bs*64 + a)*64 + b;
            int er = (bs*64 + b)*64 + a;
            s_eOut[r] = eo; s_eRev[r] = er; s_aAtom[r] = bs*64 + a;
            s_adjRev[r] = adj[er];
        }
        __syncthreads();
    }

    // ---- A-build role: thread t -> row brow, k-offset koff (4 floats), LDS shorts [4t..4t+3]
    const int rt_b = t >> 7;
    const int q_b  = (t >> 5) & 3;
    const int li_b = (t >> 1) & 15;
    const int half = t & 1;
    const int brow = rt_b*16 + li_b;
    const int koff = q_b*8 + 4*half;
    const float* aRow = nullptr;
    const unsigned short* aRowH = nullptr;
    const float* mRow = nullptr;
    float adjR = 0.f;
    if constexpr (MODE == 1){
        aRow = Asrc + (size_t)s_eRev[brow]*ASTR;
        mRow = ma + (size_t)s_aAtom[brow]*Hc;
        adjR = s_adjRev[brow];
    } else if constexpr (MODE == 2){
        int n = brow & 63, cc = brow >> 6;
        int eR = (bs0*64 + (2*mp0 + cc))*64 + n;       // row (m,n): contiguous per cc
        if constexpr (ABF) aRowH = (const unsigned short*)Asrc + (size_t)eR*ASTR;
        else               aRow  = Asrc + (size_t)eR*ASTR;
        mRow = ma + (size_t)(bs0*64 + n)*Hc;
        adjR = adj[eR];
    } else {
        int n = brow & 63, cc = brow >> 6;
        int e = (bs0*64 + n)*64 + (2*mp0 + cc);        // output edge itself
        aRow = Asrc + (size_t)e*ASTR;
        adjR = adj[e];
    }

    float pm[4], pa[4];
    auto prefetchA = [&](int kt){
        int k0 = kt*32 + koff;
        if constexpr (MODE != 0){
            if (k0 <= 296){
                if constexpr (ABF){
                    us4 v = *(const us4*)(aRowH + k0);     // 8B aligned (row pitch 600B, k0%4==0)
                    pm[0]=b2f(v.x); pm[1]=b2f(v.y); pm[2]=b2f(v.z); pm[3]=b2f(v.w);
                } else {
                    float4 v = *(const float4*)(aRow + k0);
                    pm[0]=v.x; pm[1]=v.y; pm[2]=v.z; pm[3]=v.w;
                }
                float4 w = *(const float4*)(mRow + k0);
                pa[0]=w.x; pa[1]=w.y; pa[2]=w.z; pa[3]=w.w;
            }
        } else {
            if (k0 + 3 < BFD){
                f32x4u v = *(const f32x4u*)(aRow + k0);   // 4B-aligned dwordx4
                pm[0]=v.x; pm[1]=v.y; pm[2]=v.z; pm[3]=v.w;
            } else {
                #pragma unroll
                for (int j = 0; j < 4; ++j){
                    int k = k0 + j;
                    pm[j] = (k < BFD) ? aRow[k] : 0.f;
                }
            }
        }
    };
    auto buildA = [&](int kt){
        int k0 = kt*32 + koff;
        float xv[4];
        if constexpr (MODE != 0){
            if (k0 <= 296){
                #pragma unroll
                for (int j = 0; j < 4; ++j) xv[j] = fmaf(adjR, pa[j], -pm[j]);
            } else { xv[0]=xv[1]=xv[2]=xv[3]=0.f; }
        } else {
            #pragma unroll
            for (int j = 0; j < 4; ++j) xv[j] = adjR * pm[j];
        }
        unsigned short h0,l0,h1,l1,h2,l2,h3,l3;
        split2(xv[0],h0,l0); split2(xv[1],h1,l1);
        split2(xv[2],h2,l2); split2(xv[3],h3,l3);
        uint2 hw, lw;
        hw.x = (unsigned int)h0 | ((unsigned int)h1<<16);
        hw.y = (unsigned int)h2 | ((unsigned int)h3<<16);
        lw.x = (unsigned int)l0 | ((unsigned int)l1<<16);
        lw.y = (unsigned int)l2 | ((unsigned int)l3<<16);
        *(uint2*)&sAhi[4*t] = hw;        // byte 8t: bank-linear, conflict-free
        *(uint2*)&sAlo[4*t] = lw;
    };
    auto copyB = [&](int kt){
        const unsigned short* src = WP + (size_t)kt*BSLICE;
        #pragma unroll
        for (int rep = 0; rep < 3; ++rep){
            int i = t + rep*1024;
            if (i < BSLICE/8)
                gload_lds16(src + (size_t)i*8, &sB[i*8]);
        }
    };

    // ---- compute role
    const int wv = t >> 6, lane = t & 63;
    const int li = lane & 15, quad = lane >> 4;
    const int rg = wv & 3;                       // row-tiles 2rg, 2rg+1
    const int cg = wv >> 2;
    const int c0 = cg*5;
    const int myC = (cg < 3) ? 5 : 4;

    f32x4 acc[5][2];
    #pragma unroll
    for (int c = 0; c < 5; ++c){ acc[c][0] = (f32x4){0,0,0,0}; acc[c][1] = (f32x4){0,0,0,0}; }

    prefetchA(0);

    // MODE1/2: preload ib into acc (epilogue loads vanish; overlaps kt0 staging)
    if constexpr (MODE != 0){
        #pragma unroll
        for (int c = 0; c < 5; ++c){
            if (c < myC){
                int h = (c0 + c)*16 + li;
                if (h < Hc){
                    #pragma unroll
                    for (int r2 = 0; r2 < 2; ++r2)
                        #pragma unroll
                        for (int i = 0; i < 4; ++i){
                            int row = (2*rg + r2)*16 + quad*4 + i;
                            int e;
                            if constexpr (MODE == 1) e = s_eOut[row];
                            else e = (bs0*64 + (row & 63))*64 + (2*mp0 + (row >> 6));
                            if constexpr (IBF)
                                acc[c][r2][i] = b2f(((const unsigned short*)ib)[(size_t)e*Hc + h]);
                            else
                                acc[c][r2][i] = ib[(size_t)e*Hc + h];
                        }
                }
            }
        }
    }

    for (int kt = 0; kt < NKT; ++kt){
        if (kt) bar_only();                      // B1: pure barrier (prefetchA stays in flight)
        copyB(kt);                               // 3 async gload_lds (L2-hot)
        buildA(kt);                              // consumes pm/pa (compiler-counted vmcnt)
        bar_drain();                             // vmcnt(0)+lgkm(0): copyB + sA writes visible
        if (kt+1 < NKT) prefetchA(kt+1);         // HBM latency spans full compute(kt) + B1
        __builtin_amdgcn_s_setprio(1);
        U4 a0h, a0l, a1h, a1l;
        a0h.u = *(const uint4*)&sAhi[((2*rg  )*64 + lane)*8];
        a0l.u = *(const uint4*)&sAlo[((2*rg  )*64 + lane)*8];
        a1h.u = *(const uint4*)&sAhi[((2*rg+1)*64 + lane)*8];
        a1l.u = *(const uint4*)&sAlo[((2*rg+1)*64 + lane)*8];
        #pragma unroll
        for (int c = 0; c < 5; ++c){
            if (c < myC){
                U4 bh, bl;
                bh.u = *(const uint4*)&sB[        (c0+c)*512 + lane*8];
                bl.u = *(const uint4*)&sB[BHALF + (c0+c)*512 + lane*8];
                acc[c][0] = __builtin_amdgcn_mfma_f32_16x16x32_bf16(a0h.v, bl.v, acc[c][0], 0,0,0);
                acc[c][0] = __builtin_amdgcn_mfma_f32_16x16x32_bf16(a0l.v, bh.v, acc[c][0], 0,0,0);
                acc[c][0] = __builtin_amdgcn_mfma_f32_16x16x32_bf16(a0h.v, bh.v, acc[c][0], 0,0,0);
                acc[c][1] = __builtin_amdgcn_mfma_f32_16x16x32_bf16(a1h.v, bl.v, acc[c][1], 0,0,0);
                acc[c][1] = __builtin_amdgcn_mfma_f32_16x16x32_bf16(a1l.v, bh.v, acc[c][1], 0,0,0);
                acc[c][1] = __builtin_amdgcn_mfma_f32_16x16x32_bf16(a1h.v, bh.v, acc[c][1], 0,0,0);
            }
        }
        __builtin_amdgcn_s_setprio(0);
    }

    if constexpr (MODE == 1){
        // ---- closed-pair epilogue: stores only
        int eO[2][4]; float smv[2][4];
        #pragma unroll
        for (int r2 = 0; r2 < 2; ++r2)
            #pragma unroll
            for (int i = 0; i < 4; ++i){
                int row = (2*rg + r2)*16 + quad*4 + i;
                int e = s_eOut[row];
                eO[r2][i] = e;
                smv[r2][i] = sm[e];
            }
        #pragma unroll
        for (int c = 0; c < 5; ++c){
            if (c >= myC) continue;
            int h = (c0 + c)*16 + li;
            if (h >= Hc) continue;
            #pragma unroll
            for (int r2 = 0; r2 < 2; ++r2)
                #pragma unroll
                for (int i = 0; i < 4; ++i){
                    size_t off = (size_t)eO[r2][i]*Hc + h;
                    dst[off] = reluf(acc[c][r2][i]) * smv[r2][i];
                }
        }
    } else {
        // ---- column-pair epilogue: store + fused column reduction (agg)
        __syncthreads();                          // all sB reads done -> reuse sB as sRed
        float* sRedS = (float*)sB;                // [16 waves][304]
        float* sRedM = sRedS + 16*304;
        int eO[2][4]; float smv[2][4];
        #pragma unroll
        for (int r2 = 0; r2 < 2; ++r2)
            #pragma unroll
            for (int i = 0; i < 4; ++i){
                int row = (2*rg + r2)*16 + quad*4 + i;
                int e = (bs0*64 + (row & 63))*64 + (2*mp0 + (row >> 6));
                eO[r2][i] = e;
                if constexpr (MODE == 2) smv[r2][i] = sm[e];
            }
        #pragma unroll
        for (int c = 0; c < 5; ++c){
            float s8 = 0.f, m8 = -INFINITY;
            int h = (c0 + c)*16 + li;
            if (c < myC && h < Hc){
                #pragma unroll
                for (int r2 = 0; r2 < 2; ++r2)
                    #pragma unroll
                    for (int i = 0; i < 4; ++i){
                        float v = reluf(acc[c][r2][i]);
                        if constexpr (MODE == 2) v *= smv[r2][i];
                        if constexpr (DBF)
                            ((unsigned short*)dst)[(size_t)eO[r2][i]*Hc + h] = f2b(v);
                        else
                            dst[(size_t)eO[r2][i]*Hc + h] = v;
                        s8 += v; m8 = fmaxf(m8, v);
                    }
            }
            // butterfly across quads (lane bits 4,5): 32-row partial per (wave, h)
            s8 += __shfl_xor(s8, 16, 64); s8 += __shfl_xor(s8, 32, 64);
            m8 = fmaxf(m8, __shfl_xor(m8, 16, 64)); m8 = fmaxf(m8, __shfl_xor(m8, 32, 64));
            if (c < myC && quad == 0){
                sRedS[wv*304 + (c0 + c)*16 + li] = s8;
                sRedM[wv*304 + (c0 + c)*16 + li] = m8;
            }
        }
        __syncthreads();
        if (t < 608){
            int cc = t / 304, h = t - cc*304;     // cc: which column of the pair
            if (h < Hc){
                int ct = h >> 4;
                int cgf = (ct < 15) ? (ct/5) : 3;
                int w0 = (cgf << 2) + 2*cc;       // rg 2cc, 2cc+1 hold this column's rows
                float s = sRedS[w0*304 + h] + sRedS[(w0+1)*304 + h];
                float m = fmaxf(sRedM[w0*304 + h], sRedM[(w0+1)*304 + h]);
                float agg = s * (1.f/(1.f + expf(-m)));
                size_t o = (size_t)(bs0*64 + 2*mp0 + cc)*Hc + h;
                if constexpr (MODE == 0) aggb[o] += agg;   // message_atom += agg (sole owner)
                else                     aggb[o]  = agg;   // agg buffer
            }
        }
    }
}

// ---------------- ma += agg (tiny, float4)
__global__ __launch_bounds__(256) void k_ma_add(float* __restrict__ ma, const float* __restrict__ aggb){
    int i = blockIdx.x*256 + threadIdx.x;
    if (i < ROWS*Hc/4){
        float4 a = ((const float4*)aggb)[i];
        float4 v = ((float4*)ma)[i];
        v.x += a.x; v.y += a.y; v.z += a.z; v.w += a.w;
        ((float4*)ma)[i] = v;
    }
}

// ---------------- K3: agg (fallback final only)
__global__ __launch_bounds__(320) void k_agg(const float* __restrict__ message_bond,
        float* __restrict__ message_atom, float* __restrict__ agg_out, int final_mode){
    int t = threadIdx.x;
    int r = t / 80, c = t - r*80;
    if (c >= 75) return;
    int row = blockIdx.x*4 + r;
    int bs = row >> 6, m = row & 63;
    size_t base = ((size_t)(bs*Nc)*Nc + m)*(size_t)Hc + (size_t)c*4;
    float4 s  = {0.f, 0.f, 0.f, 0.f};
    float4 mx = {-INFINITY, -INFINITY, -INFINITY, -INFINITY};
    #pragma unroll 4
    for (int n = 0; n < Nc; ++n){
        float4 v = *(const float4*)(message_bond + base + (size_t)n*Nc*Hc);
        s.x += v.x; s.y += v.y; s.z += v.z; s.w += v.w;
        mx.x = fmaxf(mx.x, v.x); mx.y = fmaxf(mx.y, v.y);
        mx.z = fmaxf(mx.z, v.z); mx.w = fmaxf(mx.w, v.w);
    }
    float4 agg;
    agg.x = s.x * (1.f/(1.f + expf(-mx.x)));
    agg.y = s.y * (1.f/(1.f + expf(-mx.y)));
    agg.z = s.z * (1.f/(1.f + expf(-mx.z)));
    agg.w = s.w * (1.f/(1.f + expf(-mx.w)));
    size_t o = (size_t)row*Hc + (size_t)c*4;
    if (final_mode){
        *(float4*)(agg_out + o) = agg;
    } else {
        float4 cur = *(const float4*)(message_atom + o);
        cur.x += agg.x; cur.y += agg.y; cur.z += agg.z; cur.w += agg.w;
        *(float4*)(message_atom + o) = cur;
    }
}

// ---------------- K4: res[n,m] = dot(ma[n],ma[m])*adj[n,m]; sm = softmax over n per (b,s,m)
__global__ __launch_bounds__(256) void k_resonance_softmax(const float* __restrict__ message_atom,
        const float* __restrict__ adj, float* __restrict__ sm){
    int bs = blockIdx.x >> 6, m = blockIdx.x & 63;
    __shared__ float am[Hc];
    __shared__ float res[Nc];
    for (int d = threadIdx.x; d < Hc; d += blockDim.x)
        am[d] = message_atom[((size_t)(bs*Nc)+m)*Hc + d];
    __syncthreads();
    int wave = threadIdx.x >> 6, lane = threadIdx.x & 63;
    for (int n = wave; n < Nc; n += 4){
        const float* man = message_atom + ((size_t)(bs*Nc)+n)*Hc;
        float acc = 0.f;
        for (int d = lane; d < Hc; d += 64) acc = fmaf(man[d], am[d], acc);
        #pragma unroll
        for (int off = 32; off > 0; off >>= 1) acc += __shfl_xor(acc, off, 64);
        if (lane == 0) res[n] = acc * adj[((size_t)(bs*Nc)+n)*Nc + m];
    }
    __syncthreads();
    if (threadIdx.x < Nc){
        float v = res[threadIdx.x];
        float mx = v;
        #pragma unroll
        for (int off = 32; off > 0; off >>= 1) mx = fmaxf(mx, __shfl_xor(mx, off, 64));
        float e = expf(v - mx);
        float ssum = e;
        #pragma unroll
        for (int off = 32; off > 0; off >>= 1) ssum += __shfl_xor(ssum, off, 64);
        sm[((size_t)(bs*Nc)+threadIdx.x)*Nc + m] = e / ssum;
    }
}

// ---------------- K6: atom_hiddens = relu([agg|message_atom|input_atom] @ W_o + b_o)
#define R7 4
__global__ __launch_bounds__(320) void k_output(const float* __restrict__ agg,
        const float* __restrict__ message_atom, const float* __restrict__ input_atom,
        const float* __restrict__ W_o, const float* __restrict__ b_o, float* __restrict__ out){
    __shared__ float xin[R7][3*Hc];
    int r0 = blockIdx.x * R7;
    for (int idx = threadIdx.x; idx < R7*3*Hc; idx += blockDim.x){
        int r = idx / (3*Hc), k = idx - r*(3*Hc);
        int row = r0 + r;
        float v;
        if (k < Hc)           v = agg[(size_t)row*Hc + k];
        else if (k < 2*Hc)    v = message_atom[(size_t)row*Hc + (k - Hc)];
        else                  v = input_atom[(size_t)row*Hc + (k - 2*Hc)];
        xin[r][k] = v;
    }
    __syncthreads();
    int h = threadIdx.x;
    if (h < Hc){
        float acc[R7];
        #pragma unroll
        for (int r=0;r<R7;r++) acc[r] = b_o[h];
        for (int d = 0; d < 3*Hc; ++d){
            float w = W_o[d*Hc + h];
            #pragma unroll
            for (int r=0;r<R7;r++) acc[r] = fmaf(xin[r][d], w, acc[r]);
        }
        #pragma unroll
        for (int r=0;r<R7;r++) out[(size_t)(r0+r)*Hc + h] = reluf(acc[r]);
    }
}

extern "C" void kernel_launch(void* const* d_in, const int* in_sizes, int n_in,
                              void* d_out, int out_size, void* d_ws, size_t ws_size,
                              hipStream_t stream){
    const float* f_atoms  = (const float*)d_in[0];
    const float* f_bonds  = (const float*)d_in[1];
    const float* adj      = (const float*)d_in[2];
    const float* W_i_atom = (const float*)d_in[3];
    const float* W_i_bond = (const float*)d_in[4];
    const float* W_h0     = (const float*)d_in[5];
    const float* W_h1     = (const float*)d_in[6];
    const float* W_o      = (const float*)d_in[7];
    const float* b_o      = (const float*)d_in[8];

    float* out = (float*)d_out;
    float* atom_hiddens = out;                       // [2048, 300]
    float* mb_out = out + (size_t)ROWS*Hc;           // [131072, 300] fp32 (output #2)

    float* wsf = (float*)d_ws;
    float* input_atom   = wsf; wsf += (size_t)ROWS*Hc;
    float* message_atom = wsf; wsf += (size_t)ROWS*Hc;
    float* sm           = wsf; wsf += (size_t)EDGES;
    float* aggb         = wsf; wsf += (size_t)ROWS*Hc;          // fused agg buffer (2.4MB)
    float* ib           = wsf; wsf += (size_t)EDGES*Hc;         // 157MB plane (fp32 fallback / bf16 main)
    unsigned short* wsu = (unsigned short*)wsf;
    unsigned short* WP0 = wsu; wsu += 10*BSLICE;
    unsigned short* WP1 = wsu; wsu += 10*BSLICE;
    unsigned short* WPb = wsu; wsu += 5*BSLICE;

    size_t used = (size_t)((char*)wsu - (char*)d_ws);
    used = (used + 255) & ~(size_t)255;
    unsigned short* mbx = nullptr;                   // step-1 output, bf16 (78.6MB)
    if (ws_size >= used + (size_t)EDGES*Hc*sizeof(unsigned short))
        mbx = (unsigned short*)((char*)d_ws + used);

    k_atom_embed<<<ROWS, 320, 0, stream>>>(f_atoms, W_i_atom, input_atom, message_atom);
    k_prep_wp2<<<(10*BSLICE + 255)/256, 256, 0, stream>>>(W_h0, Hc, 10, WP0);
    k_prep_wp2<<<(10*BSLICE + 255)/256, 256, 0, stream>>>(W_h1, Hc, 10, WP1);
    k_prep_wp2<<<(5*BSLICE + 255)/256, 256, 0, stream>>>(W_i_bond, BFD, 5, WPb);
    if (mbx){
        // ib stored as bf16 plane (79MB): written by MODE0, read 3x (step-1 A, step-1/2 C-init)
        unsigned short* ibh = (unsigned short*)ib;
        // bond embed (column-pair) + fused agg#1 (message_atom += agg); ib -> bf16
        k_gemm_t<0,0,1,0><<<BS*32, 1024, 0, stream>>>(f_bonds, WPb, nullptr, adj, nullptr, nullptr, (float*)ibh, message_atom);
        k_resonance_softmax<<<ROWS, 256, 0, stream>>>(message_atom, adj, sm);
        // step 1: A=ib(bf16) C-init=ib(bf16) -> mbx (bf16) + fused agg#2 -> aggb
        k_gemm_t<2,1,1,1><<<BS*32, 1024, 0, stream>>>((const float*)ibh, WP0, message_atom, adj, sm, (const float*)ibh, (float*)mbx, aggb);
        k_ma_add<<<(ROWS*Hc/4 + 255)/256, 256, 0, stream>>>(message_atom, aggb);
        k_resonance_softmax<<<ROWS, 256, 0, stream>>>(message_atom, adj, sm);
        // step 2: A=mbx(bf16) C-init=ib(bf16) -> mb_out (fp32) + fused FINAL agg -> aggb
        k_gemm_t<2,1,0,1><<<BS*32, 1024, 0, stream>>>((const float*)mbx, WP1, message_atom, adj, sm, (const float*)ibh, mb_out, aggb);
        k_output<<<ROWS/R7, 320, 0, stream>>>(aggb, message_atom, input_atom, W_o, b_o, atom_hiddens);
    } else {
        // fallback (R3 path, all fp32): step 1 -> mb_out, in-place closed-pair step 2, separate final agg
        float* agg_out = ib;   // alias: ib dead after step-2 GEMM
        k_gemm_t<0,0,0,0><<<BS*32, 1024, 0, stream>>>(f_bonds, WPb, nullptr, adj, nullptr, nullptr, ib, message_atom);
        k_resonance_softmax<<<ROWS, 256, 0, stream>>>(message_atom, adj, sm);
        k_gemm_t<2,0,0,0><<<BS*32, 1024, 0, stream>>>(ib, WP0, message_atom, adj, sm, ib, mb_out, aggb);
        k_ma_add<<<(ROWS*Hc/4 + 255)/256, 256, 0, stream>>>(message_atom, aggb);
        k_resonance_softmax<<<ROWS, 256, 0, stream>>>(message_atom, adj, sm);
        k_gemm_t<1,0,0,0><<<BS*32, 1024, 0, stream>>>(mb_out, WP1, message_atom, adj, sm, ib, mb_out, nullptr);
        k_agg<<<ROWS/4, 320, 0, stream>>>(mb_out, nullptr, agg_out, 1);
        k_output<<<ROWS/R7, 320, 0, stream>>>(agg_out, message_atom, input_atom, W_o, b_o, atom_hiddens);
    }
}